// Round 6
// baseline (566.151 us; speedup 1.0000x reference)
//
#include <hip/hip_runtime.h>
#include <math.h>

#define HW_ (512 * 512)   // 2^18
#define C_ 64
#define K_ 16
#define B_ 8
#define NTHREADS_ 524288  // 2048 blocks x 256

// Transpose conv_w [K][C] -> wt [C][K]; per-channel weights become 16
// contiguous floats at a wave-uniform address (scalarizes to s_load).
__global__ __launch_bounds__(256) void transpose_w_kernel(const float* __restrict__ w,
                                                          float* __restrict__ wt) {
    int i = blockIdx.x * blockDim.x + threadIdx.x;  // 0..1023
    if (i < K_ * C_) {
        int k = i >> 6;
        int c = i & 63;
        wt[c * K_ + k] = w[i];
    }
}

// Per-pixel epilogue: log_softmax form + gumbel-max, same fp expression order
// as the jax reference (byte-identical to the passing R0/R3 kernels), but
// consuming pre-loaded unif registers.
__device__ __forceinline__ void epilogue(const float* acc, const float4* u4,
                                         const float* __restrict__ palette,
                                         float& cr, float& cg, float& cb) {
    float m = acc[0];
    #pragma unroll
    for (int k = 1; k < K_; ++k) m = fmaxf(m, acc[k]);
    float s = 0.0f;
    #pragma unroll
    for (int k = 0; k < K_; ++k) s += expf(acc[k] - m);
    float ls = logf(s);

    float best = -INFINITY;
    int bi = 0;
    #pragma unroll
    for (int q = 0; q < 4; ++q) {
        float4 v = u4[q];
        float g0 = -logf(-logf(v.x + 1e-20f) + 1e-20f);
        float g1 = -logf(-logf(v.y + 1e-20f) + 1e-20f);
        float g2 = -logf(-logf(v.z + 1e-20f) + 1e-20f);
        float g3 = -logf(-logf(v.w + 1e-20f) + 1e-20f);
        float t0 = (acc[q * 4 + 0] - m) - ls + g0;
        float t1 = (acc[q * 4 + 1] - m) - ls + g1;
        float t2 = (acc[q * 4 + 2] - m) - ls + g2;
        float t3 = (acc[q * 4 + 3] - m) - ls + g3;
        if (t0 > best) { best = t0; bi = q * 4 + 0; }
        if (t1 > best) { best = t1; bi = q * 4 + 1; }
        if (t2 > best) { best = t2; bi = q * 4 + 2; }
        if (t3 > best) { best = t3; bi = q * 4 + 3; }
    }
    cr = palette[bi * 3 + 0];
    cg = palette[bi * 3 + 1];
    cb = palette[bi * 3 + 2];
}

// 1 pixel/thread per round (wave = 64 consecutive pixels), 4 rounds.
// Continuous cross-pixel software pipeline:
//   - channel groups fully unrolled, depth-2 prefetch (8 loads in flight)
//   - unif prefetched at group 6 (issued BEFORE next-pixel x loads, so the
//     epilogue's vmcnt wait for unif does not drain them)
//   - next pixel's group-0 x loads issued at group 7, staying in flight
//     through the epilogue -> no load-dead window.
__global__ __launch_bounds__(256, 8) void quantizer_kernel(
    const float* __restrict__ x,        // [B][C][HW]
    const float* __restrict__ wt,       // [C][K]
    const float* __restrict__ bias,     // [K]
    const float* __restrict__ palette,  // [K][3]
    const float* __restrict__ unif,     // [B*HW][K]
    float* __restrict__ out)            // [B][3][HW]
{
    const int tid = blockIdx.x * blockDim.x + threadIdx.x;   // 0..524287

    // base pointer for pixel p = tid (round 0)
    int p = tid;
    int b = p >> 18;
    int hw = p & (HW_ - 1);
    const float* xp = x + (size_t)(b * C_) * HW_ + hw;

    float cur[8], nxt[8];
    #pragma unroll
    for (int i = 0; i < 8; ++i) cur[i] = xp[(size_t)i * HW_];

    #pragma unroll 1
    for (int r = 0; r < 4; ++r) {
        p = tid + r * NTHREADS_;
        b = p >> 18;
        hw = p & (HW_ - 1);

        float acc[K_];
        #pragma unroll
        for (int k = 0; k < K_; ++k) acc[k] = bias[k];

        float4 u4[4];
        const float* xpn = xp;   // next pixel base (set at g==7)

        #pragma unroll
        for (int g = 0; g < 8; ++g) {
            if (g == 6) {
                // unif prefetch: issued before next-pixel x loads (queue order)
                const float4* up4 = reinterpret_cast<const float4*>(unif + (size_t)p * K_);
                u4[0] = up4[0]; u4[1] = up4[1]; u4[2] = up4[2]; u4[3] = up4[3];
            }
            if (g < 7) {
                #pragma unroll
                for (int i = 0; i < 8; ++i)
                    nxt[i] = xp[(size_t)(g * 8 + 8 + i) * HW_];
            } else if (r < 3) {
                int pn = tid + (r + 1) * NTHREADS_;
                int bn = pn >> 18;
                int hwn = pn & (HW_ - 1);
                xpn = x + (size_t)(bn * C_) * HW_ + hwn;
                #pragma unroll
                for (int i = 0; i < 8; ++i)
                    nxt[i] = xpn[(size_t)i * HW_];
            }

            const float* wp = wt + (g * 8) * K_;   // wave-uniform -> s_load
            #pragma unroll
            for (int k = 0; k < K_; ++k) {
                float a = acc[k];
                #pragma unroll
                for (int i = 0; i < 8; ++i)
                    a = fmaf(cur[i], wp[i * K_ + k], a);
                acc[k] = a;
            }
            if (g < 7 || r < 3) {
                #pragma unroll
                for (int i = 0; i < 8; ++i) cur[i] = nxt[i];   // renamed away (unrolled)
            }
        }
        xp = xpn;

        // epilogue overlaps the next pixel's in-flight x loads
        float cr, cg, cb;
        epilogue(acc, u4, palette, cr, cg, cb);

        size_t obase = (size_t)b * 3 * HW_ + (size_t)hw;
        out[obase]                   = cr;
        out[obase + (size_t)HW_]     = cg;
        out[obase + 2 * (size_t)HW_] = cb;
    }
}

extern "C" void kernel_launch(void* const* d_in, const int* in_sizes, int n_in,
                              void* d_out, int out_size, void* d_ws, size_t ws_size,
                              hipStream_t stream) {
    const float* x       = (const float*)d_in[0];
    const float* conv_w  = (const float*)d_in[1];
    const float* conv_b  = (const float*)d_in[2];
    const float* palette = (const float*)d_in[3];
    const float* unif    = (const float*)d_in[4];
    float* out = (float*)d_out;
    float* wt  = (float*)d_ws;   // K_*C_*4 = 4 KiB scratch

    hipLaunchKernelGGL(transpose_w_kernel, dim3(4), dim3(256), 0, stream, conv_w, wt);

    // 2048 blocks x 256 threads = 524288 threads, 4 pixels each.
    hipLaunchKernelGGL(quantizer_kernel, dim3(2048), dim3(256), 0, stream,
                       x, wt, conv_b, palette, unif, out);
}

// Round 7
// 198.338 us; speedup vs baseline: 2.8545x; 2.8545x over previous
//
#include <hip/hip_runtime.h>
#include <math.h>

#define HW_ (512 * 512)   // 2^18
#define C_ 64
#define K_ 16
#define B_ 8
#define TOTAL_ (B_ * HW_)

// Transpose conv_w [K][C] -> wt [C][K]; per-channel weights become 16
// contiguous floats at a wave-uniform address (scalarizes to s_load).
__global__ __launch_bounds__(256) void transpose_w_kernel(const float* __restrict__ w,
                                                          float* __restrict__ wt) {
    int i = blockIdx.x * blockDim.x + threadIdx.x;  // 0..1023
    if (i < K_ * C_) {
        int k = i >> 6;
        int c = i & 63;
        wt[c * K_ + k] = w[i];
    }
}

// Per-pixel epilogue: log_softmax form + gumbel-max, same fp expression order
// as the jax reference (byte-identical to the passing R0/R3 kernels), fed
// from pre-loaded unif registers.
__device__ __forceinline__ void epilogue(const float* acc, const float4* u4,
                                         const float* __restrict__ palette,
                                         float& cr, float& cg, float& cb) {
    float m = acc[0];
    #pragma unroll
    for (int k = 1; k < K_; ++k) m = fmaxf(m, acc[k]);
    float s = 0.0f;
    #pragma unroll
    for (int k = 0; k < K_; ++k) s += expf(acc[k] - m);
    float ls = logf(s);

    float best = -INFINITY;
    int bi = 0;
    #pragma unroll
    for (int q = 0; q < 4; ++q) {
        float4 v = u4[q];
        float g0 = -logf(-logf(v.x + 1e-20f) + 1e-20f);
        float g1 = -logf(-logf(v.y + 1e-20f) + 1e-20f);
        float g2 = -logf(-logf(v.z + 1e-20f) + 1e-20f);
        float g3 = -logf(-logf(v.w + 1e-20f) + 1e-20f);
        float t0 = (acc[q * 4 + 0] - m) - ls + g0;
        float t1 = (acc[q * 4 + 1] - m) - ls + g1;
        float t2 = (acc[q * 4 + 2] - m) - ls + g2;
        float t3 = (acc[q * 4 + 3] - m) - ls + g3;
        if (t0 > best) { best = t0; bi = q * 4 + 0; }
        if (t1 > best) { best = t1; bi = q * 4 + 1; }
        if (t2 > best) { best = t2; bi = q * 4 + 2; }
        if (t3 > best) { best = t3; bi = q * 4 + 3; }
    }
    cr = palette[bi * 3 + 0];
    cg = palette[bi * 3 + 1];
    cb = palette[bi * 3 + 2];
}

// R3's proven structure (1 px/thread, rotation-loop depth-2 x pipeline,
// 8 waves/SIMD) + ONE change: unif is prefetched at the top of channel
// group 7, where the nxt[] buffer is dead — register-neutral, and the
// group-7 FMAs + early epilogue ops cover the unif load latency.
__global__ __launch_bounds__(256, 8) void quantizer_kernel(
    const float* __restrict__ x,        // [B][C][HW]
    const float* __restrict__ wt,       // [C][K]
    const float* __restrict__ bias,     // [K]
    const float* __restrict__ palette,  // [K][3]
    const float* __restrict__ unif,     // [B*HW][K]
    float* __restrict__ out)            // [B][3][HW]
{
    int tid = blockIdx.x * blockDim.x + threadIdx.x;   // 524288 threads

    #pragma unroll 1
    for (int p = tid; p < TOTAL_; p += 524288) {       // 4 pixel iterations
        int b = p >> 18;
        int hw = p & (HW_ - 1);
        const float* xp = x + (size_t)b * C_ * HW_ + (size_t)hw;

        float acc[K_];
        #pragma unroll
        for (int k = 0; k < K_; ++k) acc[k] = bias[k];

        // prologue: load channels 0..7
        float cur[8], nxt[8];
        #pragma unroll
        for (int i = 0; i < 8; ++i) cur[i] = xp[(size_t)i * HW_];

        float4 u4[4];

        // steady state: issue 8 loads for group g+1 (or unif at g==7),
        // then 128 FMAs for group g. Per-(pixel,k) accumulation order is
        // ascending c 0..63 — bitwise identical to the passing R0/R3 chain.
        #pragma unroll 1
        for (int g = 0; g < 8; ++g) {
            int c0 = g * 8;
            if (g < 7) {
                #pragma unroll
                for (int i = 0; i < 8; ++i)
                    nxt[i] = xp[(size_t)(c0 + 8 + i) * HW_];
            } else {
                // nxt[] is dead here; u4 takes its register space.
                const float4* up4 = reinterpret_cast<const float4*>(unif + (size_t)p * K_);
                u4[0] = up4[0]; u4[1] = up4[1]; u4[2] = up4[2]; u4[3] = up4[3];
            }
            const float* wp = wt + c0 * K_;   // wave-uniform -> s_load
            #pragma unroll
            for (int k = 0; k < K_; ++k) {
                float a = acc[k];
                #pragma unroll
                for (int i = 0; i < 8; ++i)
                    a = fmaf(cur[i], wp[i * K_ + k], a);
                acc[k] = a;
            }
            if (g < 7) {
                #pragma unroll
                for (int i = 0; i < 8; ++i) cur[i] = nxt[i];
            }
        }

        float cr, cg, cb;
        epilogue(acc, u4, palette, cr, cg, cb);

        size_t obase = (size_t)b * 3 * HW_ + (size_t)hw;
        out[obase]                   = cr;
        out[obase + (size_t)HW_]     = cg;
        out[obase + 2 * (size_t)HW_] = cb;
    }
}

extern "C" void kernel_launch(void* const* d_in, const int* in_sizes, int n_in,
                              void* d_out, int out_size, void* d_ws, size_t ws_size,
                              hipStream_t stream) {
    const float* x       = (const float*)d_in[0];
    const float* conv_w  = (const float*)d_in[1];
    const float* conv_b  = (const float*)d_in[2];
    const float* palette = (const float*)d_in[3];
    const float* unif    = (const float*)d_in[4];
    float* out = (float*)d_out;
    float* wt  = (float*)d_ws;   // K_*C_*4 = 4 KiB scratch

    hipLaunchKernelGGL(transpose_w_kernel, dim3(4), dim3(256), 0, stream, conv_w, wt);

    // 2048 blocks x 256 = 524288 threads, 4 pixels each (R3 mapping)
    hipLaunchKernelGGL(quantizer_kernel, dim3(2048), dim3(256), 0, stream,
                       x, wt, conv_b, palette, unif, out);
}

// Round 8
// 183.800 us; speedup vs baseline: 3.0802x; 1.0791x over previous
//
#include <hip/hip_runtime.h>
#include <math.h>

#define HW_ (512 * 512)   // 2^18
#define C_ 64
#define K_ 16
#define B_ 8
#define TOTAL_ (B_ * HW_)

typedef float f32x2 __attribute__((ext_vector_type(2)));

// Transpose conv_w [K][C] -> wt [C][K]; per-channel weights become 16
// contiguous floats at a wave-uniform address (scalarizes to s_load).
__global__ __launch_bounds__(256) void transpose_w_kernel(const float* __restrict__ w,
                                                          float* __restrict__ wt) {
    int i = blockIdx.x * blockDim.x + threadIdx.x;  // 0..1023
    if (i < K_ * C_) {
        int k = i >> 6;
        int c = i & 63;
        wt[c * K_ + k] = w[i];
    }
}

// Per-pixel epilogue: log_softmax form + gumbel-max, same fp expression order
// as the jax reference — byte-identical to the passing R0/R3 kernels,
// including the unif loads issued HERE (R6 proved hoisting them regresses).
__device__ __forceinline__ void epilogue(const float* acc, const float4* up4,
                                         const float* __restrict__ palette,
                                         float& cr, float& cg, float& cb) {
    float m = acc[0];
    #pragma unroll
    for (int k = 1; k < K_; ++k) m = fmaxf(m, acc[k]);
    float s = 0.0f;
    #pragma unroll
    for (int k = 0; k < K_; ++k) s += expf(acc[k] - m);
    float ls = logf(s);

    float best = -INFINITY;
    int bi = 0;
    #pragma unroll
    for (int q = 0; q < 4; ++q) {
        float4 v = up4[q];
        float g0 = -logf(-logf(v.x + 1e-20f) + 1e-20f);
        float g1 = -logf(-logf(v.y + 1e-20f) + 1e-20f);
        float g2 = -logf(-logf(v.z + 1e-20f) + 1e-20f);
        float g3 = -logf(-logf(v.w + 1e-20f) + 1e-20f);
        float t0 = (acc[q * 4 + 0] - m) - ls + g0;
        float t1 = (acc[q * 4 + 1] - m) - ls + g1;
        float t2 = (acc[q * 4 + 2] - m) - ls + g2;
        float t3 = (acc[q * 4 + 3] - m) - ls + g3;
        if (t0 > best) { best = t0; bi = q * 4 + 0; }
        if (t1 > best) { best = t1; bi = q * 4 + 1; }
        if (t2 > best) { best = t2; bi = q * 4 + 2; }
        if (t3 > best) { best = t3; bi = q * 4 + 3; }
    }
    cr = palette[bi * 3 + 0];
    cg = palette[bi * 3 + 1];
    cb = palette[bi * 3 + 2];
}

// R3's proven structure verbatim (1 px/thread, rotation-loop depth-2 x
// pipeline, epilogue-internal unif loads, 8 waves/SIMD). ONE change: the
// accumulator is f32x2[8] over k-pairs and the inner FMA uses
// __builtin_elementwise_fma -> v_pk_fma_f32 (2 fp32/instr), halving the
// dominant VALU term. Per-element chain order (ascending c, fma) unchanged
// -> bitwise-identical logits.
__global__ __launch_bounds__(256, 8) void quantizer_kernel(
    const float* __restrict__ x,        // [B][C][HW]
    const float* __restrict__ wt,       // [C][K]
    const float* __restrict__ bias,     // [K]
    const float* __restrict__ palette,  // [K][3]
    const float* __restrict__ unif,     // [B*HW][K]
    float* __restrict__ out)            // [B][3][HW]
{
    int tid = blockIdx.x * blockDim.x + threadIdx.x;   // 524288 threads

    #pragma unroll 1
    for (int p = tid; p < TOTAL_; p += 524288) {       // 4 pixel iterations
        int b = p >> 18;
        int hw = p & (HW_ - 1);
        const float* xp = x + (size_t)b * C_ * HW_ + (size_t)hw;

        f32x2 acc2[8];
        const f32x2* b2 = reinterpret_cast<const f32x2*>(bias);
        #pragma unroll
        for (int j = 0; j < 8; ++j) acc2[j] = b2[j];

        // prologue: load channels 0..7
        float cur[8], nxt[8];
        #pragma unroll
        for (int i = 0; i < 8; ++i) cur[i] = xp[(size_t)i * HW_];

        // steady state: issue 8 loads for group g+1, then 64 packed FMAs for
        // group g. Per-(pixel,k) accumulation order is ascending c 0..63.
        #pragma unroll 1
        for (int g = 0; g < 8; ++g) {
            int c0 = g * 8;
            if (g < 7) {
                #pragma unroll
                for (int i = 0; i < 8; ++i)
                    nxt[i] = xp[(size_t)(c0 + 8 + i) * HW_];
            }
            const float* wp = wt + c0 * K_;   // wave-uniform -> s_load
            #pragma unroll
            for (int i = 0; i < 8; ++i) {
                f32x2 xv2 = {cur[i], cur[i]};
                const f32x2* wp2 = reinterpret_cast<const f32x2*>(wp + i * K_);
                #pragma unroll
                for (int j = 0; j < 8; ++j)
                    acc2[j] = __builtin_elementwise_fma(xv2, wp2[j], acc2[j]);
            }
            if (g < 7) {
                #pragma unroll
                for (int i = 0; i < 8; ++i) cur[i] = nxt[i];
            }
        }

        // unpack (static indexing only — stays in registers)
        float acc[K_];
        #pragma unroll
        for (int j = 0; j < 8; ++j) {
            acc[2 * j]     = acc2[j].x;
            acc[2 * j + 1] = acc2[j].y;
        }

        const float4* up4 = reinterpret_cast<const float4*>(unif + (size_t)p * K_);
        float cr, cg, cb;
        epilogue(acc, up4, palette, cr, cg, cb);

        size_t obase = (size_t)b * 3 * HW_ + (size_t)hw;
        out[obase]                   = cr;
        out[obase + (size_t)HW_]     = cg;
        out[obase + 2 * (size_t)HW_] = cb;
    }
}

extern "C" void kernel_launch(void* const* d_in, const int* in_sizes, int n_in,
                              void* d_out, int out_size, void* d_ws, size_t ws_size,
                              hipStream_t stream) {
    const float* x       = (const float*)d_in[0];
    const float* conv_w  = (const float*)d_in[1];
    const float* conv_b  = (const float*)d_in[2];
    const float* palette = (const float*)d_in[3];
    const float* unif    = (const float*)d_in[4];
    float* out = (float*)d_out;
    float* wt  = (float*)d_ws;   // K_*C_*4 = 4 KiB scratch

    hipLaunchKernelGGL(transpose_w_kernel, dim3(4), dim3(256), 0, stream, conv_w, wt);

    // 2048 blocks x 256 = 524288 threads, 4 pixels each (R3 mapping)
    hipLaunchKernelGGL(quantizer_kernel, dim3(2048), dim3(256), 0, stream,
                       x, wt, conv_b, palette, unif, out);
}

// Round 9
// 166.420 us; speedup vs baseline: 3.4019x; 1.1044x over previous
//
#include <hip/hip_runtime.h>
#include <math.h>

#define HW_ (512 * 512)   // 2^18
#define C_ 64
#define K_ 16
#define B_ 8
#define TOTAL_ (B_ * HW_)

// Transpose conv_w [K][C] -> wt [C][K]; per-channel weights become 16
// contiguous floats at a wave-uniform address (scalarizes to s_load).
__global__ __launch_bounds__(256) void transpose_w_kernel(const float* __restrict__ w,
                                                          float* __restrict__ wt) {
    int i = blockIdx.x * blockDim.x + threadIdx.x;  // 0..1023
    if (i < K_ * C_) {
        int k = i >> 6;
        int c = i & 63;
        wt[c * K_ + k] = w[i];
    }
}

// Per-pixel epilogue: log_softmax form + gumbel-max, same fp expression order
// as the jax reference — byte-identical to the passing R0/R3 kernels,
// including the unif loads issued HERE (R6 proved hoisting them regresses).
__device__ __forceinline__ void epilogue(const float* acc, const float4* up4,
                                         const float* __restrict__ palette,
                                         float& cr, float& cg, float& cb) {
    float m = acc[0];
    #pragma unroll
    for (int k = 1; k < K_; ++k) m = fmaxf(m, acc[k]);
    float s = 0.0f;
    #pragma unroll
    for (int k = 0; k < K_; ++k) s += expf(acc[k] - m);
    float ls = logf(s);

    float best = -INFINITY;
    int bi = 0;
    #pragma unroll
    for (int q = 0; q < 4; ++q) {
        float4 v = up4[q];
        float g0 = -logf(-logf(v.x + 1e-20f) + 1e-20f);
        float g1 = -logf(-logf(v.y + 1e-20f) + 1e-20f);
        float g2 = -logf(-logf(v.z + 1e-20f) + 1e-20f);
        float g3 = -logf(-logf(v.w + 1e-20f) + 1e-20f);
        float t0 = (acc[q * 4 + 0] - m) - ls + g0;
        float t1 = (acc[q * 4 + 1] - m) - ls + g1;
        float t2 = (acc[q * 4 + 2] - m) - ls + g2;
        float t3 = (acc[q * 4 + 3] - m) - ls + g3;
        if (t0 > best) { best = t0; bi = q * 4 + 0; }
        if (t1 > best) { best = t1; bi = q * 4 + 1; }
        if (t2 > best) { best = t2; bi = q * 4 + 2; }
        if (t3 > best) { best = t3; bi = q * 4 + 3; }
    }
    cr = palette[bi * 3 + 0];
    cg = palette[bi * 3 + 1];
    cb = palette[bi * 3 + 2];
}

// R3's pixel body verbatim (rotation-loop depth-2 x pipeline, epilogue-
// internal unif loads), but ONE pixel per thread with an 8192-block grid:
// waves retire after one pixel, so the HW dispatcher staggers wave phases
// (no phase-locked VMEM/VALU convoys) and per-wave live state shrinks.
__global__ __launch_bounds__(256, 8) void quantizer_kernel(
    const float* __restrict__ x,        // [B][C][HW]
    const float* __restrict__ wt,       // [C][K]
    const float* __restrict__ bias,     // [K]
    const float* __restrict__ palette,  // [K][3]
    const float* __restrict__ unif,     // [B*HW][K]
    float* __restrict__ out)            // [B][3][HW]
{
    int p = blockIdx.x * blockDim.x + threadIdx.x;   // pixel id, exact cover
    int b = p >> 18;
    int hw = p & (HW_ - 1);
    const float* xp = x + (size_t)b * C_ * HW_ + (size_t)hw;

    float acc[K_];
    #pragma unroll
    for (int k = 0; k < K_; ++k) acc[k] = bias[k];

    // prologue: load channels 0..7
    float cur[8], nxt[8];
    #pragma unroll
    for (int i = 0; i < 8; ++i) cur[i] = xp[(size_t)i * HW_];

    // steady state: issue 8 loads for group g+1, then 128 FMAs for group g.
    // Per-(pixel,k) accumulation order is ascending c 0..63 — bitwise
    // identical to the passing R0/R3 chain.
    #pragma unroll 1
    for (int g = 0; g < 8; ++g) {
        int c0 = g * 8;
        if (g < 7) {
            #pragma unroll
            for (int i = 0; i < 8; ++i)
                nxt[i] = xp[(size_t)(c0 + 8 + i) * HW_];
        }
        const float* wp = wt + c0 * K_;   // wave-uniform -> s_load
        #pragma unroll
        for (int k = 0; k < K_; ++k) {
            float a = acc[k];
            #pragma unroll
            for (int i = 0; i < 8; ++i)
                a = fmaf(cur[i], wp[i * K_ + k], a);
            acc[k] = a;
        }
        if (g < 7) {
            #pragma unroll
            for (int i = 0; i < 8; ++i) cur[i] = nxt[i];
        }
    }

    const float4* up4 = reinterpret_cast<const float4*>(unif + (size_t)p * K_);
    float cr, cg, cb;
    epilogue(acc, up4, palette, cr, cg, cb);

    size_t obase = (size_t)b * 3 * HW_ + (size_t)hw;
    out[obase]                   = cr;
    out[obase + (size_t)HW_]     = cg;
    out[obase + 2 * (size_t)HW_] = cb;
}

extern "C" void kernel_launch(void* const* d_in, const int* in_sizes, int n_in,
                              void* d_out, int out_size, void* d_ws, size_t ws_size,
                              hipStream_t stream) {
    const float* x       = (const float*)d_in[0];
    const float* conv_w  = (const float*)d_in[1];
    const float* conv_b  = (const float*)d_in[2];
    const float* palette = (const float*)d_in[3];
    const float* unif    = (const float*)d_in[4];
    float* out = (float*)d_out;
    float* wt  = (float*)d_ws;   // K_*C_*4 = 4 KiB scratch

    hipLaunchKernelGGL(transpose_w_kernel, dim3(4), dim3(256), 0, stream, conv_w, wt);

    // 8192 blocks x 256 threads = 2M threads, exactly 1 pixel each.
    hipLaunchKernelGGL(quantizer_kernel, dim3(8192), dim3(256), 0, stream,
                       x, wt, conv_b, palette, unif, out);
}